// Round 1
// baseline (429.128 us; speedup 1.0000x reference)
//
#include <hip/hip_runtime.h>
#include <hip/hip_bf16.h>

// GPT2 self-attention: x[2,2048,1024] fp32 -> QKV gemm -> 16-head causal attn -> proj.
// Round 0: correctness-first bf16 MFMA pipeline, 3 kernels.

#define SEQ 2048
#define DM 1024
#define HD 64
#define NHEAD 16
#define BHTOT 32  // B * NHEAD

typedef unsigned short u16;
typedef __bf16 bf16_t;
typedef bf16_t bf16x8 __attribute__((ext_vector_type(8)));
typedef float f32x4 __attribute__((ext_vector_type(4)));

__device__ __forceinline__ u16 f2bf(float f) {
  unsigned u = __float_as_uint(f);
  u += 0x7fffu + ((u >> 16) & 1u);
  return (u16)(u >> 16);
}

__device__ __forceinline__ f32x4 mfma16(uint4 a, uint4 b, f32x4 c) {
  return __builtin_amdgcn_mfma_f32_16x16x32_bf16(
      __builtin_bit_cast(bf16x8, a), __builtin_bit_cast(bf16x8, b), c, 0, 0, 0);
}

// ---------------- QKV GEMM: X[4096,1024] @ W[1024,3072] + b ----------------
// Epilogue scatters bf16 into head-major Q(scaled)/K/V buffers [BH][SEQ][HD].
__global__ __launch_bounds__(256) void qkv_gemm(
    const float* __restrict__ X, const float* __restrict__ W,
    const float* __restrict__ bias,
    u16* __restrict__ qb, u16* __restrict__ kb, u16* __restrict__ vb) {
  __shared__ u16 Al[128][40];  // A tile, rows x k (pitch 40 to dodge conflicts)
  __shared__ u16 Bl[128][40];  // B tile transposed: [n][k]
  const int tid = threadIdx.x;
  const int m0 = blockIdx.y * 128;
  const int n0 = blockIdx.x * 128;
  const int w = tid >> 6, lane = tid & 63;
  const int lr = lane & 15, lg = lane >> 4;
  const int wm = (w >> 1) * 64, wn = (w & 1) * 64;

  f32x4 acc[4][4] = {};

  for (int kk = 0; kk < DM; kk += 32) {
    __syncthreads();
    // stage A: 128x32 fp32 -> bf16
#pragma unroll
    for (int i = 0; i < 4; ++i) {
      int f = tid + 256 * i;
      int row = f >> 3;
      int k4 = (f & 7) << 2;
      float4 v = *(const float4*)(X + (size_t)(m0 + row) * DM + kk + k4);
      uint2 pk;
      pk.x = (unsigned)f2bf(v.x) | ((unsigned)f2bf(v.y) << 16);
      pk.y = (unsigned)f2bf(v.z) | ((unsigned)f2bf(v.w) << 16);
      *(uint2*)&Al[row][k4] = pk;
    }
    // stage B transposed: W[kk+kr][n0+n] -> Bl[n][kr]
#pragma unroll
    for (int i = 0; i < 4; ++i) {
      int f = tid + 256 * i;
      int kr = f >> 5;
      int n4 = (f & 31) << 2;
      float4 v = *(const float4*)(W + (size_t)(kk + kr) * 3072 + n0 + n4);
      Bl[n4 + 0][kr] = f2bf(v.x);
      Bl[n4 + 1][kr] = f2bf(v.y);
      Bl[n4 + 2][kr] = f2bf(v.z);
      Bl[n4 + 3][kr] = f2bf(v.w);
    }
    __syncthreads();
    uint4 af[4], bfr[4];
#pragma unroll
    for (int mi = 0; mi < 4; ++mi)
      af[mi] = *(const uint4*)&Al[wm + mi * 16 + lr][lg * 8];
#pragma unroll
    for (int ni = 0; ni < 4; ++ni)
      bfr[ni] = *(const uint4*)&Bl[wn + ni * 16 + lr][lg * 8];
#pragma unroll
    for (int mi = 0; mi < 4; ++mi)
#pragma unroll
      for (int ni = 0; ni < 4; ++ni)
        acc[mi][ni] = mfma16(af[mi], bfr[ni], acc[mi][ni]);
  }

  // epilogue: bias + scatter to head-major bf16 (Q scaled by 1/sqrt(64))
#pragma unroll
  for (int mi = 0; mi < 4; ++mi) {
#pragma unroll
    for (int ni = 0; ni < 4; ++ni) {
#pragma unroll
      for (int r = 0; r < 4; ++r) {
        int m = m0 + wm + mi * 16 + lg * 4 + r;
        int n = n0 + wn + ni * 16 + lr;
        float v = acc[mi][ni][r] + bias[n];
        int part = n >> 10;
        int d = n & 1023;
        int h = d >> 6, dim = d & 63;
        int b = m >> 11, s = m & 2047;
        size_t off = ((size_t)(b * NHEAD + h) * SEQ + s) * HD + dim;
        if (part == 0)      qb[off] = f2bf(v * 0.125f);
        else if (part == 1) kb[off] = f2bf(v);
        else                vb[off] = f2bf(v);
      }
    }
  }
}

// ---------------- causal flash attention ----------------
// grid (SEQ/64, BH); block 256 = 4 waves x 16 q-rows.
__global__ __launch_bounds__(256) void attn_kernel(
    const u16* __restrict__ Q, const u16* __restrict__ K,
    const u16* __restrict__ V, u16* __restrict__ O) {
  __shared__ u16 Vl[64][40];     // V transposed: [dim][kv]
  __shared__ u16 Pl[4][16][40];  // per-wave P tile: [q][kv]
  const int tid = threadIdx.x;
  const int bh = blockIdx.y;
  const int q0 = blockIdx.x * 64;
  const int w = tid >> 6, lane = tid & 63;
  const int lr = lane & 15, lg = lane >> 4;
  const int qw0 = q0 + w * 16;

  const u16* Qb = Q + (size_t)bh * SEQ * HD;
  const u16* Kb = K + (size_t)bh * SEQ * HD;
  const u16* Vb = V + (size_t)bh * SEQ * HD;

  uint4 aq[2];
#pragma unroll
  for (int ks = 0; ks < 2; ++ks)
    aq[ks] = *(const uint4*)(Qb + (size_t)(qw0 + lr) * HD + ks * 32 + lg * 8);

  f32x4 o[4] = {};
  float M[4], L[4];
#pragma unroll
  for (int r = 0; r < 4; ++r) { M[r] = -1e30f; L[r] = 0.f; }

  const int nkv = (q0 >> 5) + 2;  // causal: kv blocks cover [0, q0+64)
  for (int t = 0; t < nkv; ++t) {
    const int kv0 = t * 32;
    __syncthreads();
    // stage V transposed into LDS
    {
      int kvr = tid >> 3;
      int d8 = (tid & 7) << 3;
      uint4 vv = *(const uint4*)(Vb + (size_t)(kv0 + kvr) * HD + d8);
      const u16* pv = (const u16*)&vv;
#pragma unroll
      for (int j = 0; j < 8; ++j) Vl[d8 + j][kvr] = pv[j];
    }
    // scores = Q @ K^T (K frags straight from global, contiguous 16B)
    f32x4 s[2] = {};
#pragma unroll
    for (int nf = 0; nf < 2; ++nf)
#pragma unroll
      for (int ks = 0; ks < 2; ++ks) {
        uint4 bk = *(const uint4*)(Kb + (size_t)(kv0 + nf * 16 + lr) * HD + ks * 32 + lg * 8);
        s[nf] = mfma16(aq[ks], bk, s[nf]);
      }
    // causal mask + online softmax (rows live in 16-lane groups)
#pragma unroll
    for (int r = 0; r < 4; ++r) {
      const int q_abs = qw0 + lg * 4 + r;
#pragma unroll
      for (int nf = 0; nf < 2; ++nf) {
        int kv_abs = kv0 + nf * 16 + lr;
        if (kv_abs > q_abs) s[nf][r] = -1e30f;
      }
      float m2 = fmaxf(s[0][r], s[1][r]);
      m2 = fmaxf(m2, __shfl_xor(m2, 1));
      m2 = fmaxf(m2, __shfl_xor(m2, 2));
      m2 = fmaxf(m2, __shfl_xor(m2, 4));
      m2 = fmaxf(m2, __shfl_xor(m2, 8));
      float newM = fmaxf(M[r], m2);
      float sc = __expf(M[r] - newM);
      float p0 = __expf(s[0][r] - newM);
      float p1 = __expf(s[1][r] - newM);
      s[0][r] = p0; s[1][r] = p1;
      float sum = p0 + p1;
      sum += __shfl_xor(sum, 1);
      sum += __shfl_xor(sum, 2);
      sum += __shfl_xor(sum, 4);
      sum += __shfl_xor(sum, 8);
      L[r] = L[r] * sc + sum;
      M[r] = newM;
#pragma unroll
      for (int nf = 0; nf < 4; ++nf) o[nf][r] *= sc;
    }
    // P -> LDS (fix D-layout -> A-layout mismatch)
#pragma unroll
    for (int r = 0; r < 4; ++r)
#pragma unroll
      for (int nf = 0; nf < 2; ++nf)
        Pl[w][lg * 4 + r][nf * 16 + lr] = f2bf(s[nf][r]);
    __syncthreads();
    // PV
    uint4 ap = *(const uint4*)&Pl[w][lr][lg * 8];
#pragma unroll
    for (int nf = 0; nf < 4; ++nf) {
      uint4 bv = *(const uint4*)&Vl[nf * 16 + lr][lg * 8];
      o[nf] = mfma16(ap, bv, o[nf]);
    }
  }
  // normalize + write merged-head bf16 [B][S][DM]
  const int b = bh >> 4, h = bh & 15;
#pragma unroll
  for (int nf = 0; nf < 4; ++nf)
#pragma unroll
    for (int r = 0; r < 4; ++r) {
      int s_abs = qw0 + lg * 4 + r;
      float val = o[nf][r] / L[r];
      O[((size_t)b * SEQ + s_abs) * DM + h * HD + nf * 16 + lr] = f2bf(val);
    }
}

// ---------------- proj GEMM: A_bf16[4096,1024] @ W[1024,1024] + b -> fp32 ----------------
__global__ __launch_bounds__(256) void proj_gemm(
    const u16* __restrict__ A, const float* __restrict__ W,
    const float* __restrict__ bias, float* __restrict__ out) {
  __shared__ u16 Al[128][40];
  __shared__ u16 Bl[128][40];
  const int tid = threadIdx.x;
  const int m0 = blockIdx.y * 128;
  const int n0 = blockIdx.x * 128;
  const int w = tid >> 6, lane = tid & 63;
  const int lr = lane & 15, lg = lane >> 4;
  const int wm = (w >> 1) * 64, wn = (w & 1) * 64;

  f32x4 acc[4][4] = {};

  for (int kk = 0; kk < DM; kk += 32) {
    __syncthreads();
    // stage A (already bf16): 128x32, 16B copies
#pragma unroll
    for (int i = 0; i < 2; ++i) {
      int f = tid + 256 * i;
      int row = f >> 2;
      int k8 = (f & 3) << 3;
      uint4 v = *(const uint4*)(A + (size_t)(m0 + row) * DM + kk + k8);
      *(uint4*)&Al[row][k8] = v;
    }
    // stage B transposed
#pragma unroll
    for (int i = 0; i < 4; ++i) {
      int f = tid + 256 * i;
      int kr = f >> 5;
      int n4 = (f & 31) << 2;
      float4 v = *(const float4*)(W + (size_t)(kk + kr) * DM + n0 + n4);
      Bl[n4 + 0][kr] = f2bf(v.x);
      Bl[n4 + 1][kr] = f2bf(v.y);
      Bl[n4 + 2][kr] = f2bf(v.z);
      Bl[n4 + 3][kr] = f2bf(v.w);
    }
    __syncthreads();
    uint4 af[4], bfr[4];
#pragma unroll
    for (int mi = 0; mi < 4; ++mi)
      af[mi] = *(const uint4*)&Al[wm + mi * 16 + lr][lg * 8];
#pragma unroll
    for (int ni = 0; ni < 4; ++ni)
      bfr[ni] = *(const uint4*)&Bl[wn + ni * 16 + lr][lg * 8];
#pragma unroll
    for (int mi = 0; mi < 4; ++mi)
#pragma unroll
      for (int ni = 0; ni < 4; ++ni)
        acc[mi][ni] = mfma16(af[mi], bfr[ni], acc[mi][ni]);
  }

#pragma unroll
  for (int mi = 0; mi < 4; ++mi)
#pragma unroll
    for (int ni = 0; ni < 4; ++ni)
#pragma unroll
      for (int r = 0; r < 4; ++r) {
        int m = m0 + wm + mi * 16 + lg * 4 + r;
        int n = n0 + wn + ni * 16 + lr;
        out[(size_t)m * DM + n] = acc[mi][ni][r] + bias[n];
      }
}

extern "C" void kernel_launch(void* const* d_in, const int* in_sizes, int n_in,
                              void* d_out, int out_size, void* d_ws, size_t ws_size,
                              hipStream_t stream) {
  const float* x      = (const float*)d_in[0];
  const float* qkv_w  = (const float*)d_in[1];
  const float* qkv_b  = (const float*)d_in[2];
  const float* proj_w = (const float*)d_in[3];
  const float* proj_b = (const float*)d_in[4];
  float* out = (float*)d_out;

  // workspace: Q, K, V head-major bf16 + attn output bf16 (4 x 8 MB = 33.5 MB)
  const size_t per = (size_t)BHTOT * SEQ * HD;  // 4194304 elems
  u16* qb = (u16*)d_ws;
  u16* kb = qb + per;
  u16* vb = kb + per;
  u16* ab = vb + per;

  dim3 blk(256);
  qkv_gemm<<<dim3(24, 32), blk, 0, stream>>>(x, qkv_w, qkv_b, qb, kb, vb);
  attn_kernel<<<dim3(SEQ / 64, BHTOT), blk, 0, stream>>>(qb, kb, vb, ab);
  proj_gemm<<<dim3(DM / 128, 32), blk, 0, stream>>>(ab, proj_w, proj_b, out);
}

// Round 3
// 161.907 us; speedup vs baseline: 2.6505x; 2.6505x over previous
//
#include <hip/hip_runtime.h>
#include <hip/hip_bf16.h>

// GPT2 self-attention: x[2,2048,1024] fp32 -> QKV gemm -> 16-head causal attn -> proj.
// Round 3: fix P-relayout (shfl_xor, unambiguous semantics); m97-structure GEMMs
// (bf16 pre-convert + transposed weights + global_load_lds width-16).

#define SEQ 2048
#define DM 1024
#define HD 64
#define NHEAD 16
#define BHTOT 32  // B * NHEAD

typedef unsigned short u16;
typedef __bf16 bf16_t;
typedef bf16_t bf16x8 __attribute__((ext_vector_type(8)));
typedef float f32x4 __attribute__((ext_vector_type(4)));
typedef float f32x16 __attribute__((ext_vector_type(16)));

__device__ __forceinline__ u16 f2bf(float f) {
  unsigned u = __float_as_uint(f);
  u += 0x7fffu + ((u >> 16) & 1u);
  return (u16)(u >> 16);
}

__device__ __forceinline__ f32x4 mfma16(uint4 a, uint4 b, f32x4 c) {
  return __builtin_amdgcn_mfma_f32_16x16x32_bf16(
      __builtin_bit_cast(bf16x8, a), __builtin_bit_cast(bf16x8, b), c, 0, 0, 0);
}

__device__ __forceinline__ f32x16 mfma32(uint4 a, uint4 b, f32x16 c) {
  return __builtin_amdgcn_mfma_f32_32x32x16_bf16(
      __builtin_bit_cast(bf16x8, a), __builtin_bit_cast(bf16x8, b), c, 0, 0, 0);
}

__device__ __forceinline__ unsigned cvtpk(float lo, float hi) {
  unsigned d;
  asm("v_cvt_pk_bf16_f32 %0, %1, %2" : "=v"(d) : "v"(lo), "v"(hi));
  return d;
}

__device__ __forceinline__ void gload_lds16(const u16* g, void* l) {
  __builtin_amdgcn_global_load_lds(
      (const __attribute__((address_space(1))) unsigned*)g,
      (__attribute__((address_space(3))) unsigned*)l, 16, 0, 0);
}

// ---------------- fp32 -> bf16 convert (x) ----------------
__global__ __launch_bounds__(256) void cvt_bf16(const float* __restrict__ in,
                                                u16* __restrict__ out) {
  int i = (blockIdx.x * 256 + threadIdx.x) * 4;
  float4 v = *(const float4*)(in + i);
  uint2 pk;
  pk.x = (unsigned)f2bf(v.x) | ((unsigned)f2bf(v.y) << 16);
  pk.y = (unsigned)f2bf(v.z) | ((unsigned)f2bf(v.w) << 16);
  *(uint2*)(out + i) = pk;
}

// ---------------- W[K][N] fp32 -> Wt[N][K] bf16 ----------------
__global__ __launch_bounds__(256) void transpose_w(const float* __restrict__ W,
                                                   u16* __restrict__ Wt,
                                                   int K, int N) {
  __shared__ u16 t[32][33];
  const int n0 = blockIdx.x * 32, k0 = blockIdx.y * 32;
  const int tx = threadIdx.x & 31, ty = threadIdx.x >> 5;
#pragma unroll
  for (int i = 0; i < 4; ++i) {
    int k = ty + i * 8;
    t[tx][k] = f2bf(W[(size_t)(k0 + k) * N + n0 + tx]);
  }
  __syncthreads();
#pragma unroll
  for (int i = 0; i < 4; ++i) {
    int n = ty + i * 8;
    Wt[(size_t)(n0 + n) * K + k0 + tx] = t[n][tx];
  }
}

// ---------------- QKV GEMM (m97 structure): xb[4096,1024] @ WqkvT[3072,1024]^T ----------------
__global__ __launch_bounds__(256) void qkv_gemm(
    const u16* __restrict__ A, const u16* __restrict__ Bt,
    const float* __restrict__ bias,
    u16* __restrict__ qb, u16* __restrict__ kb, u16* __restrict__ vb) {
  __shared__ u16 Al[128 * 32];  // [row][k] pitch 32 (linear, required by global_load_lds)
  __shared__ u16 Bl[128 * 32];
  const int tid = threadIdx.x;
  const int m0 = blockIdx.y * 128;
  const int n0 = blockIdx.x * 128;
  const int w = tid >> 6, lane = tid & 63;
  const int lr = lane & 15, lg = lane >> 4;
  const int wm = (w >> 1) * 64, wn = (w & 1) * 64;
  const int Kd = DM;

  f32x4 acc[4][4] = {};

  for (int kk = 0; kk < Kd; kk += 32) {
    __syncthreads();
#pragma unroll
    for (int i = 0; i < 2; ++i) {
      int off = (i * 4 + w) * 1024 + lane * 16;  // byte offset in 8KB tile
      int row = off >> 6, colb = off & 63;
      gload_lds16(A + (size_t)(m0 + row) * Kd + kk + (colb >> 1),
                  (char*)Al + (i * 4 + w) * 1024);
      gload_lds16(Bt + (size_t)(n0 + row) * Kd + kk + (colb >> 1),
                  (char*)Bl + (i * 4 + w) * 1024);
    }
    __syncthreads();
    uint4 af[4], bfr[4];
#pragma unroll
    for (int mi = 0; mi < 4; ++mi)
      af[mi] = *(const uint4*)(Al + (wm + mi * 16 + lr) * 32 + lg * 8);
#pragma unroll
    for (int ni = 0; ni < 4; ++ni)
      bfr[ni] = *(const uint4*)(Bl + (wn + ni * 16 + lr) * 32 + lg * 8);
#pragma unroll
    for (int mi = 0; mi < 4; ++mi)
#pragma unroll
      for (int ni = 0; ni < 4; ++ni)
        acc[mi][ni] = mfma16(af[mi], bfr[ni], acc[mi][ni]);
  }

  // epilogue: bias + scatter (Q scaled by 1/sqrt(64); V transposed [BH][HD][SEQ])
#pragma unroll
  for (int mi = 0; mi < 4; ++mi) {
#pragma unroll
    for (int ni = 0; ni < 4; ++ni) {
#pragma unroll
      for (int r = 0; r < 4; ++r) {
        int m = m0 + wm + mi * 16 + lg * 4 + r;
        int n = n0 + wn + ni * 16 + lr;
        float v = acc[mi][ni][r] + bias[n];
        int part = n >> 10;
        int d = n & 1023;
        int h = d >> 6, dim = d & 63;
        int b = m >> 11, s = m & 2047;
        int bh = b * NHEAD + h;
        if (part == 0)
          qb[((size_t)bh * SEQ + s) * HD + dim] = f2bf(v * 0.125f);
        else if (part == 1)
          kb[((size_t)bh * SEQ + s) * HD + dim] = f2bf(v);
        else
          vb[((size_t)bh * HD + dim) * SEQ + s] = f2bf(v);
      }
    }
  }
}

// ---------------- causal flash attention, LDS-free ----------------
// grid (BH, 16); block 256 = 4 waves, wave w handles q-tile {y,31-y,32+y,63-y}[w] (32 rows).
// S^T = mfma(K, Q): lane owns q-col = lane&31.  O^T = mfma(V^T, P^T): same col.
__global__ __launch_bounds__(256) void attn_kernel(
    const u16* __restrict__ Q, const u16* __restrict__ K,
    const u16* __restrict__ Vt, u16* __restrict__ O) {
  const int lane = threadIdx.x & 63;
  const int w = threadIdx.x >> 6;
  const int r31 = lane & 31;
  const int hi = lane >> 5;
  const int bh = blockIdx.x;
  const int y = blockIdx.y;
  const int qt = (w == 0) ? y : (w == 1) ? (31 - y) : (w == 2) ? (32 + y) : (63 - y);
  const int q0w = qt * 32;

  const u16* Qb = Q + (size_t)bh * SEQ * HD;
  const u16* Kb = K + (size_t)bh * SEQ * HD;
  const u16* Vb = Vt + (size_t)bh * HD * SEQ;

  uint4 qf[4];
#pragma unroll
  for (int ks = 0; ks < 4; ++ks)
    qf[ks] = *(const uint4*)(Qb + (size_t)(q0w + r31) * HD + ks * 16 + hi * 8);

  f32x16 ot0 = {}, ot1 = {};
  float M = -1e30f, L = 0.f;

  const int nst = (q0w >> 6) + 1;
  for (int t = 0; t < nst; ++t) {
    const int kv0 = t << 6;
    // QK^T (swapped): S^T[kv][q]
    f32x16 s0 = {}, s1 = {};
#pragma unroll
    for (int ks = 0; ks < 4; ++ks) {
      uint4 kf0 = *(const uint4*)(Kb + (size_t)(kv0 + r31) * HD + ks * 16 + hi * 8);
      uint4 kf1 = *(const uint4*)(Kb + (size_t)(kv0 + 32 + r31) * HD + ks * 16 + hi * 8);
      s0 = mfma32(kf0, qf[ks], s0);
      s1 = mfma32(kf1, qf[ks], s1);
    }
    // causal mask (only the last kv block crosses the diagonal)
    if (t == nst - 1) {
      const int q_abs = q0w + r31;
#pragma unroll
      for (int i = 0; i < 16; ++i) {
        int row = (i & 3) + 8 * (i >> 2) + 4 * hi;
        if (kv0 + row > q_abs) s0[i] = -1e30f;
        if (kv0 + 32 + row > q_abs) s1[i] = -1e30f;
      }
    }
    // online softmax: one q-row per lane (duplicated across halves)
    float pm = s0[0];
#pragma unroll
    for (int i = 1; i < 16; ++i) pm = fmaxf(pm, s0[i]);
#pragma unroll
    for (int i = 0; i < 16; ++i) pm = fmaxf(pm, s1[i]);
    pm = fmaxf(pm, __shfl_xor(pm, 32));
    const float newM = fmaxf(M, pm);
    const float sc = __expf(M - newM);
    M = newM;
    float rs = 0.f;
#pragma unroll
    for (int i = 0; i < 16; ++i) { s0[i] = __expf(s0[i] - newM); rs += s0[i]; }
#pragma unroll
    for (int i = 0; i < 16; ++i) { s1[i] = __expf(s1[i] - newM); rs += s1[i]; }
    rs += __shfl_xor(rs, 32);
    L = L * sc + rs;
#pragma unroll
    for (int i = 0; i < 16; ++i) { ot0[i] *= sc; ot1[i] *= sc; }

    // P^T -> bf16 B-fragments (k = hi*8 + j). Lane owns rows {0..3,8..11}+4hi (per
    // 16-slice: {0..3}+4hi and {8..11}+4hi). Cross-half exchange via shfl_xor(32):
    //   hi=0 word0=(c0,c1)=e01, w1=(c2,c3)=e23, w2=(c4,c5)=partner e01, w3=partner e23
    //   hi=1 word0=(c8,c9)=partner e45, w1=partner e67, w2=(c12,c13)=e45, w3=e67
    uint4 pa[4];
#define RELAYOUT(dst, v0, v1, v2, v3, v4, v5, v6, v7)                    \
    {                                                                    \
      unsigned e01 = cvtpk(v0, v1), e23 = cvtpk(v2, v3);                 \
      unsigned e45 = cvtpk(v4, v5), e67 = cvtpk(v6, v7);                 \
      unsigned p01 = __shfl_xor(e01, 32), p23 = __shfl_xor(e23, 32);     \
      unsigned p45 = __shfl_xor(e45, 32), p67 = __shfl_xor(e67, 32);     \
      dst.x = hi ? p45 : e01;                                            \
      dst.y = hi ? p67 : e23;                                            \
      dst.z = hi ? e45 : p01;                                            \
      dst.w = hi ? e67 : p23;                                            \
    }
    RELAYOUT(pa[0], s0[0], s0[1], s0[2], s0[3], s0[4], s0[5], s0[6], s0[7]);
    RELAYOUT(pa[1], s0[8], s0[9], s0[10], s0[11], s0[12], s0[13], s0[14], s0[15]);
    RELAYOUT(pa[2], s1[0], s1[1], s1[2], s1[3], s1[4], s1[5], s1[6], s1[7]);
    RELAYOUT(pa[3], s1[8], s1[9], s1[10], s1[11], s1[12], s1[13], s1[14], s1[15]);
#undef RELAYOUT

    // PV (swapped): O^T[dim][q] += V^T[dim][kv] . P^T[kv][q]
#pragma unroll
    for (int ks = 0; ks < 4; ++ks) {
      uint4 vf0 = *(const uint4*)(Vb + (size_t)r31 * SEQ + kv0 + ks * 16 + hi * 8);
      uint4 vf1 = *(const uint4*)(Vb + (size_t)(32 + r31) * SEQ + kv0 + ks * 16 + hi * 8);
      ot0 = mfma32(vf0, pa[ks], ot0);
      ot1 = mfma32(vf1, pa[ks], ot1);
    }
  }

  // normalize + write merged-head bf16 [B][S][DM]; lane's column q = r31.
  const float inv = 1.0f / L;
  const int b = bh >> 4, h = bh & 15;
  u16* Orow = O + ((size_t)b * SEQ + q0w + r31) * DM + h * HD;
#pragma unroll
  for (int g = 0; g < 4; ++g) {
    uint2 p0, p1;
    p0.x = (unsigned)f2bf(ot0[4 * g + 0] * inv) | ((unsigned)f2bf(ot0[4 * g + 1] * inv) << 16);
    p0.y = (unsigned)f2bf(ot0[4 * g + 2] * inv) | ((unsigned)f2bf(ot0[4 * g + 3] * inv) << 16);
    p1.x = (unsigned)f2bf(ot1[4 * g + 0] * inv) | ((unsigned)f2bf(ot1[4 * g + 1] * inv) << 16);
    p1.y = (unsigned)f2bf(ot1[4 * g + 2] * inv) | ((unsigned)f2bf(ot1[4 * g + 3] * inv) << 16);
    *(uint2*)(Orow + 8 * g + 4 * hi) = p0;
    *(uint2*)(Orow + 32 + 8 * g + 4 * hi) = p1;
  }
}

// ---------------- proj GEMM (m97 structure): ab[4096,1024] @ WprojT[1024,1024]^T -> fp32 ----------------
__global__ __launch_bounds__(256) void proj_gemm(
    const u16* __restrict__ A, const u16* __restrict__ Bt,
    const float* __restrict__ bias, float* __restrict__ out) {
  __shared__ u16 Al[128 * 32];
  __shared__ u16 Bl[128 * 32];
  const int tid = threadIdx.x;
  const int m0 = blockIdx.y * 128;
  const int n0 = blockIdx.x * 128;
  const int w = tid >> 6, lane = tid & 63;
  const int lr = lane & 15, lg = lane >> 4;
  const int wm = (w >> 1) * 64, wn = (w & 1) * 64;
  const int Kd = DM;

  f32x4 acc[4][4] = {};

  for (int kk = 0; kk < Kd; kk += 32) {
    __syncthreads();
#pragma unroll
    for (int i = 0; i < 2; ++i) {
      int off = (i * 4 + w) * 1024 + lane * 16;
      int row = off >> 6, colb = off & 63;
      gload_lds16(A + (size_t)(m0 + row) * Kd + kk + (colb >> 1),
                  (char*)Al + (i * 4 + w) * 1024);
      gload_lds16(Bt + (size_t)(n0 + row) * Kd + kk + (colb >> 1),
                  (char*)Bl + (i * 4 + w) * 1024);
    }
    __syncthreads();
    uint4 af[4], bfr[4];
#pragma unroll
    for (int mi = 0; mi < 4; ++mi)
      af[mi] = *(const uint4*)(Al + (wm + mi * 16 + lr) * 32 + lg * 8);
#pragma unroll
    for (int ni = 0; ni < 4; ++ni)
      bfr[ni] = *(const uint4*)(Bl + (wn + ni * 16 + lr) * 32 + lg * 8);
#pragma unroll
    for (int mi = 0; mi < 4; ++mi)
#pragma unroll
      for (int ni = 0; ni < 4; ++ni)
        acc[mi][ni] = mfma16(af[mi], bfr[ni], acc[mi][ni]);
  }

#pragma unroll
  for (int mi = 0; mi < 4; ++mi)
#pragma unroll
    for (int ni = 0; ni < 4; ++ni)
#pragma unroll
      for (int r = 0; r < 4; ++r) {
        int m = m0 + wm + mi * 16 + lg * 4 + r;
        int n = n0 + wn + ni * 16 + lr;
        out[(size_t)m * DM + n] = acc[mi][ni][r] + bias[n];
      }
}

extern "C" void kernel_launch(void* const* d_in, const int* in_sizes, int n_in,
                              void* d_out, int out_size, void* d_ws, size_t ws_size,
                              hipStream_t stream) {
  const float* x      = (const float*)d_in[0];
  const float* qkv_w  = (const float*)d_in[1];
  const float* qkv_b  = (const float*)d_in[2];
  const float* proj_w = (const float*)d_in[3];
  const float* proj_b = (const float*)d_in[4];
  float* out = (float*)d_out;

  // workspace (bf16): qb/kb [bh][s][d], vb^T [bh][d][s] (8MB each);
  // xb (x in bf16, 8MB) -- reused as attn output ab after qkv_gemm's last read;
  // wqkvT [3072][1024] (6MB); wprojT [1024][1024] (2MB).  Total 40MB.
  const size_t per = (size_t)BHTOT * SEQ * HD;  // 4194304 elems
  u16* qb = (u16*)d_ws;
  u16* kb = qb + per;
  u16* vb = kb + per;
  u16* xb = vb + per;
  u16* ab = xb;  // alias: stream-ordered reuse
  u16* wqkvT = xb + (size_t)SEQ * 2 * DM;
  u16* wprojT = wqkvT + (size_t)DM * 3 * DM / 1;  // hold area sized below

  // note: wqkvT needs 3072*1024 elems; wprojT follows it.
  wprojT = wqkvT + (size_t)3072 * DM;

  dim3 blk(256);
  cvt_bf16<<<dim3(4096), blk, 0, stream>>>(x, xb);
  transpose_w<<<dim3(96, 32), blk, 0, stream>>>(qkv_w, wqkvT, DM, 3072);
  transpose_w<<<dim3(32, 32), blk, 0, stream>>>(proj_w, wprojT, DM, DM);
  qkv_gemm<<<dim3(24, 32), blk, 0, stream>>>(xb, wqkvT, qkv_b, qb, kb, vb);
  attn_kernel<<<dim3(BHTOT, 16), blk, 0, stream>>>(qb, kb, vb, ab);
  proj_gemm<<<dim3(8, 32), blk, 0, stream>>>(ab, wprojT, proj_b, out);
}

// Round 4
// 147.977 us; speedup vs baseline: 2.9000x; 1.0941x over previous
//
#include <hip/hip_runtime.h>
#include <hip/hip_bf16.h>

// GPT2 self-attention: x[2,2048,1024] fp32 -> QKV gemm -> 16-head causal attn -> proj.
// Round 4: attn rewrite — equal-work 2-wave blocks (LPT order), K reg double-buffer,
// early V issue, masked-half skip, exp2 softmax + defer-max. GEMMs unchanged.

#define SEQ 2048
#define DM 1024
#define HD 64
#define NHEAD 16
#define BHTOT 32  // B * NHEAD

typedef unsigned short u16;
typedef __bf16 bf16_t;
typedef bf16_t bf16x8 __attribute__((ext_vector_type(8)));
typedef float f32x4 __attribute__((ext_vector_type(4)));
typedef float f32x16 __attribute__((ext_vector_type(16)));

__device__ __forceinline__ u16 f2bf(float f) {
  unsigned u = __float_as_uint(f);
  u += 0x7fffu + ((u >> 16) & 1u);
  return (u16)(u >> 16);
}

__device__ __forceinline__ f32x4 mfma16(uint4 a, uint4 b, f32x4 c) {
  return __builtin_amdgcn_mfma_f32_16x16x32_bf16(
      __builtin_bit_cast(bf16x8, a), __builtin_bit_cast(bf16x8, b), c, 0, 0, 0);
}

__device__ __forceinline__ f32x16 mfma32(uint4 a, uint4 b, f32x16 c) {
  return __builtin_amdgcn_mfma_f32_32x32x16_bf16(
      __builtin_bit_cast(bf16x8, a), __builtin_bit_cast(bf16x8, b), c, 0, 0, 0);
}

__device__ __forceinline__ unsigned cvtpk(float lo, float hi) {
  unsigned d;
  asm("v_cvt_pk_bf16_f32 %0, %1, %2" : "=v"(d) : "v"(lo), "v"(hi));
  return d;
}

__device__ __forceinline__ void gload_lds16(const u16* g, void* l) {
  __builtin_amdgcn_global_load_lds(
      (const __attribute__((address_space(1))) unsigned*)g,
      (__attribute__((address_space(3))) unsigned*)l, 16, 0, 0);
}

// ---------------- fp32 -> bf16 convert (x) ----------------
__global__ __launch_bounds__(256) void cvt_bf16(const float* __restrict__ in,
                                                u16* __restrict__ out) {
  int i = (blockIdx.x * 256 + threadIdx.x) * 4;
  float4 v = *(const float4*)(in + i);
  uint2 pk;
  pk.x = (unsigned)f2bf(v.x) | ((unsigned)f2bf(v.y) << 16);
  pk.y = (unsigned)f2bf(v.z) | ((unsigned)f2bf(v.w) << 16);
  *(uint2*)(out + i) = pk;
}

// ---------------- W[K][N] fp32 -> Wt[N][K] bf16 ----------------
__global__ __launch_bounds__(256) void transpose_w(const float* __restrict__ W,
                                                   u16* __restrict__ Wt,
                                                   int K, int N) {
  __shared__ u16 t[32][33];
  const int n0 = blockIdx.x * 32, k0 = blockIdx.y * 32;
  const int tx = threadIdx.x & 31, ty = threadIdx.x >> 5;
#pragma unroll
  for (int i = 0; i < 4; ++i) {
    int k = ty + i * 8;
    t[tx][k] = f2bf(W[(size_t)(k0 + k) * N + n0 + tx]);
  }
  __syncthreads();
#pragma unroll
  for (int i = 0; i < 4; ++i) {
    int n = ty + i * 8;
    Wt[(size_t)(n0 + n) * K + k0 + tx] = t[n][tx];
  }
}

// ---------------- QKV GEMM (m97 structure): xb[4096,1024] @ WqkvT[3072,1024]^T ----------------
__global__ __launch_bounds__(256) void qkv_gemm(
    const u16* __restrict__ A, const u16* __restrict__ Bt,
    const float* __restrict__ bias,
    u16* __restrict__ qb, u16* __restrict__ kb, u16* __restrict__ vb) {
  __shared__ u16 Al[128 * 32];  // [row][k] pitch 32 (linear, required by global_load_lds)
  __shared__ u16 Bl[128 * 32];
  const int tid = threadIdx.x;
  const int m0 = blockIdx.y * 128;
  const int n0 = blockIdx.x * 128;
  const int w = tid >> 6, lane = tid & 63;
  const int lr = lane & 15, lg = lane >> 4;
  const int wm = (w >> 1) * 64, wn = (w & 1) * 64;
  const int Kd = DM;

  f32x4 acc[4][4] = {};

  for (int kk = 0; kk < Kd; kk += 32) {
    __syncthreads();
#pragma unroll
    for (int i = 0; i < 2; ++i) {
      int off = (i * 4 + w) * 1024 + lane * 16;  // byte offset in 8KB tile
      int row = off >> 6, colb = off & 63;
      gload_lds16(A + (size_t)(m0 + row) * Kd + kk + (colb >> 1),
                  (char*)Al + (i * 4 + w) * 1024);
      gload_lds16(Bt + (size_t)(n0 + row) * Kd + kk + (colb >> 1),
                  (char*)Bl + (i * 4 + w) * 1024);
    }
    __syncthreads();
    uint4 af[4], bfr[4];
#pragma unroll
    for (int mi = 0; mi < 4; ++mi)
      af[mi] = *(const uint4*)(Al + (wm + mi * 16 + lr) * 32 + lg * 8);
#pragma unroll
    for (int ni = 0; ni < 4; ++ni)
      bfr[ni] = *(const uint4*)(Bl + (wn + ni * 16 + lr) * 32 + lg * 8);
#pragma unroll
    for (int mi = 0; mi < 4; ++mi)
#pragma unroll
      for (int ni = 0; ni < 4; ++ni)
        acc[mi][ni] = mfma16(af[mi], bfr[ni], acc[mi][ni]);
  }

  // epilogue: bias + scatter (Q scaled by log2e/sqrt(64) for exp2 softmax; V transposed)
#pragma unroll
  for (int mi = 0; mi < 4; ++mi) {
#pragma unroll
    for (int ni = 0; ni < 4; ++ni) {
#pragma unroll
      for (int r = 0; r < 4; ++r) {
        int m = m0 + wm + mi * 16 + lg * 4 + r;
        int n = n0 + wn + ni * 16 + lr;
        float v = acc[mi][ni][r] + bias[n];
        int part = n >> 10;
        int d = n & 1023;
        int h = d >> 6, dim = d & 63;
        int b = m >> 11, s = m & 2047;
        int bh = b * NHEAD + h;
        if (part == 0)
          qb[((size_t)bh * SEQ + s) * HD + dim] = f2bf(v * 0.18033688f);  // 0.125*log2(e)
        else if (part == 1)
          kb[((size_t)bh * SEQ + s) * HD + dim] = f2bf(v);
        else
          vb[((size_t)bh * HD + dim) * SEQ + s] = f2bf(v);
      }
    }
  }
}

// ---------------- causal flash attention, LDS-free ----------------
// grid 1024 = 32 j-slots (LPT: longest first) x 32 bh; block 128 = 2 waves.
// wave w -> q-tile qt = 2j+w (32 rows), both waves do exactly j+1 kv-steps.
// S^T = mfma(K, Q): lane owns q-col = lane&31.  O^T = mfma(V^T, P^T): same col.
__global__ __launch_bounds__(128) void attn_kernel(
    const u16* __restrict__ Q, const u16* __restrict__ K,
    const u16* __restrict__ Vt, u16* __restrict__ O) {
  const int lane = threadIdx.x & 63;
  const int w = threadIdx.x >> 6;  // 0..1
  const int r31 = lane & 31;
  const int hi = lane >> 5;
  const int bh = blockIdx.x & 31;
  const int j = 31 - (blockIdx.x >> 5);  // LPT: long blocks dispatch first
  const int qt = 2 * j + w;
  const int q0w = qt * 32;
  const int nst = j + 1;

  const u16* Qb = Q + (size_t)bh * SEQ * HD;
  const u16* Kb = K + (size_t)bh * SEQ * HD;
  const u16* Vb = Vt + (size_t)bh * HD * SEQ;

  uint4 qf[4];
#pragma unroll
  for (int ks = 0; ks < 4; ++ks)
    qf[ks] = *(const uint4*)(Qb + (size_t)(q0w + r31) * HD + ks * 16 + hi * 8);

  f32x16 ot0 = {}, ot1 = {};
  float M = -1e30f, L = 0.f;

#define LOADK(KF, kv0)                                                          \
  {                                                                             \
    _Pragma("unroll") for (int ks = 0; ks < 4; ++ks) {                          \
      KF[ks] = *(const uint4*)(Kb + (size_t)((kv0) + r31) * HD + ks * 16 + hi * 8); \
      KF[ks + 4] =                                                              \
          *(const uint4*)(Kb + (size_t)((kv0) + 32 + r31) * HD + ks * 16 + hi * 8); \
    }                                                                           \
  }

#define RELAYOUT(dst, S, base)                                                  \
  {                                                                             \
    unsigned e01 = cvtpk(S[base + 0], S[base + 1]), e23 = cvtpk(S[base + 2], S[base + 3]); \
    unsigned e45 = cvtpk(S[base + 4], S[base + 5]), e67 = cvtpk(S[base + 6], S[base + 7]); \
    unsigned p01 = __shfl_xor(e01, 32), p23 = __shfl_xor(e23, 32);              \
    unsigned p45 = __shfl_xor(e45, 32), p67 = __shfl_xor(e67, 32);              \
    dst.x = hi ? p45 : e01;                                                     \
    dst.y = hi ? p67 : e23;                                                     \
    dst.z = hi ? e45 : p01;                                                     \
    dst.w = hi ? e67 : p23;                                                     \
  }

#define STEP(KF, KN)                                                            \
  {                                                                             \
    const int kv0 = t << 6;                                                     \
    const bool last = (t == nst - 1);                                           \
    const bool skip1 = last && ((qt & 1) == 0); /* 2nd kv half fully masked */  \
    uint4 vf[8];                                                                \
    _Pragma("unroll") for (int ks = 0; ks < 2; ++ks) {                          \
      vf[ks] = *(const uint4*)(Vb + (size_t)r31 * SEQ + kv0 + ks * 16 + hi * 8); \
      vf[ks + 4] =                                                              \
          *(const uint4*)(Vb + (size_t)(32 + r31) * SEQ + kv0 + ks * 16 + hi * 8); \
    }                                                                           \
    if (!skip1) {                                                               \
      _Pragma("unroll") for (int ks = 2; ks < 4; ++ks) {                        \
        vf[ks] = *(const uint4*)(Vb + (size_t)r31 * SEQ + kv0 + ks * 16 + hi * 8); \
        vf[ks + 4] =                                                            \
            *(const uint4*)(Vb + (size_t)(32 + r31) * SEQ + kv0 + ks * 16 + hi * 8); \
      }                                                                         \
    }                                                                           \
    f32x16 s0 = {}, s1 = {};                                                    \
    _Pragma("unroll") for (int ks = 0; ks < 4; ++ks)                            \
        s0 = mfma32(KF[ks], qf[ks], s0);                                        \
    if (!skip1) {                                                               \
      _Pragma("unroll") for (int ks = 0; ks < 4; ++ks)                          \
          s1 = mfma32(KF[ks + 4], qf[ks], s1);                                  \
    }                                                                           \
    if (t + 1 < nst) LOADK(KN, kv0 + 64);                                       \
    if (last) {                                                                 \
      _Pragma("unroll") for (int i = 0; i < 16; ++i) {                          \
        const int row = (i & 3) + 8 * (i >> 2) + 4 * hi;                        \
        if (skip1) {                                                            \
          if (row > r31) s0[i] = -1e30f;                                        \
        } else {                                                                \
          if (row > r31) s1[i] = -1e30f;                                        \
        }                                                                       \
      }                                                                         \
    }                                                                           \
    float pm = s0[0];                                                           \
    _Pragma("unroll") for (int i = 1; i < 16; ++i) pm = fmaxf(pm, s0[i]);       \
    if (!skip1) {                                                               \
      _Pragma("unroll") for (int i = 0; i < 16; ++i) pm = fmaxf(pm, s1[i]);     \
    }                                                                           \
    pm = fmaxf(pm, __shfl_xor(pm, 32));                                         \
    if (!__all(pm - M <= 8.0f)) { /* defer-max: rescale only on real growth */  \
      const float newM = fmaxf(M, pm);                                          \
      const float sc = __builtin_exp2f(M - newM);                               \
      M = newM;                                                                 \
      L *= sc;                                                                  \
      _Pragma("unroll") for (int i = 0; i < 16; ++i) {                          \
        ot0[i] *= sc;                                                           \
        ot1[i] *= sc;                                                           \
      }                                                                         \
    }                                                                           \
    float rs = 0.f;                                                             \
    _Pragma("unroll") for (int i = 0; i < 16; ++i) {                            \
      s0[i] = __builtin_exp2f(s0[i] - M);                                       \
      rs += s0[i];                                                              \
    }                                                                           \
    if (!skip1) {                                                               \
      _Pragma("unroll") for (int i = 0; i < 16; ++i) {                          \
        s1[i] = __builtin_exp2f(s1[i] - M);                                     \
        rs += s1[i];                                                            \
      }                                                                         \
    }                                                                           \
    rs += __shfl_xor(rs, 32);                                                   \
    L += rs;                                                                    \
    uint4 pa[4];                                                                \
    RELAYOUT(pa[0], s0, 0);                                                     \
    RELAYOUT(pa[1], s0, 8);                                                     \
    if (!skip1) {                                                               \
      RELAYOUT(pa[2], s1, 0);                                                   \
      RELAYOUT(pa[3], s1, 8);                                                   \
    }                                                                           \
    _Pragma("unroll") for (int ks = 0; ks < 2; ++ks) {                          \
      ot0 = mfma32(vf[ks], pa[ks], ot0);                                        \
      ot1 = mfma32(vf[ks + 4], pa[ks], ot1);                                    \
    }                                                                           \
    if (!skip1) {                                                               \
      _Pragma("unroll") for (int ks = 2; ks < 4; ++ks) {                        \
        ot0 = mfma32(vf[ks], pa[ks], ot0);                                      \
        ot1 = mfma32(vf[ks + 4], pa[ks], ot1);                                  \
      }                                                                         \
    }                                                                           \
  }

  uint4 kA[8], kB[8];
  LOADK(kA, 0);
  int t = 0;
  for (;;) {
    STEP(kA, kB);
    if (++t >= nst) break;
    STEP(kB, kA);
    if (++t >= nst) break;
  }
#undef STEP
#undef RELAYOUT
#undef LOADK

  // normalize + write merged-head bf16 [B][S][DM]; lane's column q = r31.
  const float inv = 1.0f / L;
  const int b = bh >> 4, h = bh & 15;
  u16* Orow = O + ((size_t)b * SEQ + q0w + r31) * DM + h * HD;
#pragma unroll
  for (int g = 0; g < 4; ++g) {
    uint2 p0, p1;
    p0.x = (unsigned)f2bf(ot0[4 * g + 0] * inv) | ((unsigned)f2bf(ot0[4 * g + 1] * inv) << 16);
    p0.y = (unsigned)f2bf(ot0[4 * g + 2] * inv) | ((unsigned)f2bf(ot0[4 * g + 3] * inv) << 16);
    p1.x = (unsigned)f2bf(ot1[4 * g + 0] * inv) | ((unsigned)f2bf(ot1[4 * g + 1] * inv) << 16);
    p1.y = (unsigned)f2bf(ot1[4 * g + 2] * inv) | ((unsigned)f2bf(ot1[4 * g + 3] * inv) << 16);
    *(uint2*)(Orow + 8 * g + 4 * hi) = p0;
    *(uint2*)(Orow + 32 + 8 * g + 4 * hi) = p1;
  }
}

// ---------------- proj GEMM (m97 structure): ab[4096,1024] @ WprojT[1024,1024]^T -> fp32 ----------------
__global__ __launch_bounds__(256) void proj_gemm(
    const u16* __restrict__ A, const u16* __restrict__ Bt,
    const float* __restrict__ bias, float* __restrict__ out) {
  __shared__ u16 Al[128 * 32];
  __shared__ u16 Bl[128 * 32];
  const int tid = threadIdx.x;
  const int m0 = blockIdx.y * 128;
  const int n0 = blockIdx.x * 128;
  const int w = tid >> 6, lane = tid & 63;
  const int lr = lane & 15, lg = lane >> 4;
  const int wm = (w >> 1) * 64, wn = (w & 1) * 64;
  const int Kd = DM;

  f32x4 acc[4][4] = {};

  for (int kk = 0; kk < Kd; kk += 32) {
    __syncthreads();
#pragma unroll
    for (int i = 0; i < 2; ++i) {
      int off = (i * 4 + w) * 1024 + lane * 16;
      int row = off >> 6, colb = off & 63;
      gload_lds16(A + (size_t)(m0 + row) * Kd + kk + (colb >> 1),
                  (char*)Al + (i * 4 + w) * 1024);
      gload_lds16(Bt + (size_t)(n0 + row) * Kd + kk + (colb >> 1),
                  (char*)Bl + (i * 4 + w) * 1024);
    }
    __syncthreads();
    uint4 af[4], bfr[4];
#pragma unroll
    for (int mi = 0; mi < 4; ++mi)
      af[mi] = *(const uint4*)(Al + (wm + mi * 16 + lr) * 32 + lg * 8);
#pragma unroll
    for (int ni = 0; ni < 4; ++ni)
      bfr[ni] = *(const uint4*)(Bl + (wn + ni * 16 + lr) * 32 + lg * 8);
#pragma unroll
    for (int mi = 0; mi < 4; ++mi)
#pragma unroll
      for (int ni = 0; ni < 4; ++ni)
        acc[mi][ni] = mfma16(af[mi], bfr[ni], acc[mi][ni]);
  }

#pragma unroll
  for (int mi = 0; mi < 4; ++mi)
#pragma unroll
    for (int ni = 0; ni < 4; ++ni)
#pragma unroll
      for (int r = 0; r < 4; ++r) {
        int m = m0 + wm + mi * 16 + lg * 4 + r;
        int n = n0 + wn + ni * 16 + lr;
        out[(size_t)m * DM + n] = acc[mi][ni][r] + bias[n];
      }
}

extern "C" void kernel_launch(void* const* d_in, const int* in_sizes, int n_in,
                              void* d_out, int out_size, void* d_ws, size_t ws_size,
                              hipStream_t stream) {
  const float* x      = (const float*)d_in[0];
  const float* qkv_w  = (const float*)d_in[1];
  const float* qkv_b  = (const float*)d_in[2];
  const float* proj_w = (const float*)d_in[3];
  const float* proj_b = (const float*)d_in[4];
  float* out = (float*)d_out;

  // workspace (bf16): qb/kb [bh][s][d], vb^T [bh][d][s] (8MB each);
  // xb (x in bf16, 8MB) -- reused as attn output ab after qkv_gemm's last read;
  // wqkvT [3072][1024] (6MB); wprojT [1024][1024] (2MB).
  const size_t per = (size_t)BHTOT * SEQ * HD;  // 4194304 elems
  u16* qb = (u16*)d_ws;
  u16* kb = qb + per;
  u16* vb = kb + per;
  u16* xb = vb + per;
  u16* ab = xb;  // alias: stream-ordered reuse
  u16* wqkvT = xb + (size_t)SEQ * 2 * DM;
  u16* wprojT = wqkvT + (size_t)3072 * DM;

  dim3 blk(256);
  cvt_bf16<<<dim3(4096), blk, 0, stream>>>(x, xb);
  transpose_w<<<dim3(96, 32), blk, 0, stream>>>(qkv_w, wqkvT, DM, 3072);
  transpose_w<<<dim3(32, 32), blk, 0, stream>>>(proj_w, wprojT, DM, DM);
  qkv_gemm<<<dim3(24, 32), blk, 0, stream>>>(xb, wqkvT, qkv_b, qb, kb, vb);
  attn_kernel<<<dim3(1024), dim3(128), 0, stream>>>(qb, kb, vb, ab);
  proj_gemm<<<dim3(8, 32), blk, 0, stream>>>(ab, wprojT, proj_b, out);
}